// Round 11
// baseline (244.127 us; speedup 1.0000x reference)
//
#include <hip/hip_runtime.h>
#include <cstdint>
#include <cstddef>

#define N_  8
#define C_  256
#define HW_ 1024
#define CL_ 16
#define SZ_ (N_*C_*HW_)   // 2,097,152 elements per tensor
#define WSCALE_ 4096.0f   // 2^12 exact; folded into A, cancels in L2-norm

typedef __attribute__((ext_vector_type(8))) _Float16 half8;
typedef __attribute__((ext_vector_type(4))) float f32x4;

static __device__ __forceinline__ float tanh_fast(float x){
  x = fminf(fmaxf(x, -15.f), 15.f);
  float e = __expf(2.f * x);
  return (e - 1.f) / (e + 1.f);
}

static __device__ __forceinline__ unsigned short f2h(float x){
  _Float16 h = (_Float16)x;
  return *(unsigned short*)&h;
}

static __device__ __forceinline__ void combine16(
    const float* __restrict__ mpart, const float* __restrict__ spart,
    int base, float& m, float& rl)
{
  m = -1e30f;
  #pragma unroll
  for (int k = 0; k < 16; ++k) m = fmaxf(m, mpart[base * 16 + k]);
  float s = 0.f;
  #pragma unroll
  for (int k = 0; k < 16; ++k) s += spart[base * 16 + k] * __expf(mpart[base * 16 + k] - m);
  rl = 1.f / s;
}

#define GLD16(g, l) __builtin_amdgcn_global_load_lds( \
    (const __attribute__((address_space(1))) void*)(g), \
    (__attribute__((address_space(3))) void*)(l), 16, 0, 0)

// K1 (once): sa-dot on original fp32 inputs + fp16 mirror write (replaces k_cvt)
__global__ __launch_bounds__(256) void k_sa_dot(
    const float* __restrict__ fp1, const float* __restrict__ fp2,
    const float* __restrict__ cw1, const float* __restrict__ cw2,
    const float* __restrict__ pw1, const float* __restrict__ pw2,
    float* __restrict__ cval, float* __restrict__ pdot,
    float* __restrict__ mpart, float* __restrict__ spart,
    _Float16* __restrict__ fh1, _Float16* __restrict__ fh2)
{
  const int n = blockIdx.z, side = blockIdx.y, hw0 = blockIdx.x * 64;
  const int t = threadIdx.x, hwl = t & 63, cg = t >> 6;
  const float* __restrict__ pw = side ? pw2 : pw1;
  const float* __restrict__ cw = side ? cw2 : cw1;
  const float* __restrict__ f  = (side ? fp2 : fp1) + (size_t)n * C_ * HW_ + hw0 + hwl;
  _Float16* __restrict__ fh = (side ? fh2 : fh1) + (size_t)n * C_ * HW_ + hw0 + hwl;
  const int cb = __builtin_amdgcn_readfirstlane(cg * 64);

  float acc[17];
  #pragma unroll
  for (int l = 0; l < 17; ++l) acc[l] = 0.f;

  for (int cc = 0; cc < 64; ++cc){
    const int c = cb + cc;
    const float v = f[(size_t)c * HW_];
    fh[(size_t)c * HW_] = (_Float16)v;
    acc[16] += v * cw[c];
    #pragma unroll
    for (int l = 0; l < 16; ++l) acc[l] += v * pw[l * C_ + c];
  }

  __shared__ float red[17][4][64];
  #pragma unroll
  for (int l = 0; l < 17; ++l) red[l][cg][hwl] = acc[l];
  __syncthreads();

  if (t < 64){
    const int base = n * 2 + side;
    float xc = 0.f;
    #pragma unroll
    for (int l = 0; l < 17; ++l){
      const float s = red[l][0][t] + red[l][1][t] + red[l][2][t] + red[l][3][t];
      if (l < 16) pdot[((size_t)base * CL_ + l) * HW_ + hw0 + t] = s;
      else      { cval[(size_t)base * HW_ + hw0 + t] = s; xc = s; }
    }
    float mb = xc;
    #pragma unroll
    for (int off = 32; off; off >>= 1) mb = fmaxf(mb, __shfl_xor(mb, off));
    float e = __expf(xc - mb);
    #pragma unroll
    for (int off = 32; off; off >>= 1) e += __shfl_xor(e, off);
    if (t == 0){
      mpart[base * 16 + blockIdx.x] = mb;
      spart[base * 16 + blockIdx.x] = e;
    }
  }
}

// K_flash: fused {A-tile build + MFMA GEMM + L2-norm + residual/ReLU + next-iter sa-dot
//          (+ h/s outputs at last iter)}.  A is never materialized in global memory.
// Per step kt: phase1 = main MFMA (Xs[cur],Bs[cur]) + S-MFMA build of Bs[cur^1] for
// tile kt+1 (split-fp16 hi/lo, fp32-accurate); phase2 = X stage(kt+2) + Q build(kt+2).
__global__ __launch_bounds__(512, 2) void k_flash(
    const _Float16* __restrict__ fhc1, const _Float16* __restrict__ fhc2,
    const float* __restrict__ fpin1, const float* __restrict__ fpin2,
    float* __restrict__ fpo1, float* __restrict__ fpo2,
    _Float16* __restrict__ fhn1, _Float16* __restrict__ fhn2,
    const float* __restrict__ pw1, const float* __restrict__ pw2,
    const float* __restrict__ cw1, const float* __restrict__ cw2,
    const float* __restrict__ pb1, const float* __restrict__ pb2,
    float* __restrict__ cval, float* __restrict__ pdot,
    float* __restrict__ mpart, float* __restrict__ spart,
    float* __restrict__ out, int last)
{
  const int n = blockIdx.z, g = blockIdx.y, i0 = blockIdx.x * 64;
  const unsigned short* __restrict__ X =
      (const unsigned short*)((g ? fhc2 : fhc1) + (size_t)n * C_ * HW_);

  const int baseP = n * 2 + 1 - g;   // fcl side paired with the i-rows of A-tile
  const int baseQ = n * 2 + g;       // fcl side on the k-dim + fold weight side
  const float* __restrict__ pbP = g ? pb1 : pb2;
  const float* __restrict__ pbQ = g ? pb2 : pb1;
  const float* __restrict__ cvalP = cval + (size_t)baseP * HW_;
  const float* __restrict__ cvalQ = cval + (size_t)baseQ * HW_;
  const float* __restrict__ pdotP = pdot + (size_t)baseP * CL_ * HW_;
  const float* __restrict__ pdotQ = pdot + (size_t)baseQ * CL_ * HW_;

  float mP, rlP, mQ, rlQ;
  combine16(mpart, spart, baseP, mP, rlP);
  combine16(mpart, spart, baseQ, mQ, rlQ);

  __shared__ __align__(16) unsigned char pool[118784];
  // Xs: 0 + buf*32768 (2x32KB) | Bs: 65536 + buf*8192 (2x8KB)
  // Qt(qb): 81920 + qb*15360 {A:[Qhi|0] B:[0|Qhi] C:[Qlo'|0], each [64][40] fp16}
  // Pt: 112640 [64][40] fp16 = [Phi|Plo']  | wqs: 117760 + qb*256 (float[64])
  #define XSP(buf) ((unsigned short*)(pool + (buf) * 32768))
  #define BSP(buf) ((unsigned short*)(pool + 65536 + (buf) * 8192))
  #define QTA(qb)  ((_Float16*)(pool + 81920 + (qb) * 15360))
  #define QTB(qb)  ((_Float16*)(pool + 81920 + (qb) * 15360 + 5120))
  #define QTC(qb)  ((_Float16*)(pool + 81920 + (qb) * 15360 + 10240))
  #define PTH      ((_Float16*)(pool + 112640))
  #define WQSP(qb) ((float*)(pool + 117760 + (qb) * 256))

  const int t = threadIdx.x, w = t >> 6, l = t & 63;
  const int wr = w >> 1, wc = w & 1;

  f32x4 acc[4][2];
  #pragma unroll
  for (int fm = 0; fm < 4; ++fm)
    #pragma unroll
    for (int fn = 0; fn < 2; ++fn)
      acc[fm][fn] = (f32x4){0.f, 0.f, 0.f, 0.f};

  auto stage = [&](int buf, int k0){
    unsigned short* Xsb = XSP(buf);
    #pragma unroll
    for (int s = 0; s < 4; ++s){
      const int q = (w * 4 + s) * 64 + l;
      const int row = q >> 3;
      const int kc = (q & 7) ^ (row & 7);
      GLD16(X + (size_t)row * HW_ + k0 + kc * 8, &Xsb[(w * 4 + s) * 512]);
    }
  };

  // Q build for tile jt (writes Qt[jt&1] + wqs[jt&1])
  auto q_build = [&](int jt){
    const int qb = jt & 1;
    const int col = t & 63, lg = t >> 6;
    const int j = jt * 64 + col;
    const float wq = __expf(cvalQ[j] - mQ) * rlQ;
    if (lg == 0) WQSP(qb)[col] = WSCALE_ * wq;
    #pragma unroll
    for (int u = 0; u < 2; ++u){
      const int lq = lg * 2 + u;
      const float q = wq * pdotQ[(size_t)lq * HW_ + j] + pbQ[lq];
      const _Float16 qh = (_Float16)q;
      const _Float16 ql = (_Float16)((q - (float)qh) * 256.0f);
      QTA(qb)[col * 40 + lq] = qh;
      QTB(qb)[col * 40 + 16 + lq] = qh;
      QTC(qb)[col * 40 + lq] = ql;
    }
  };

  // S-tile build for tile jt -> Bs[bw]; S = PhiQhi + 2^-8*(Plo'Qhi + PhiQlo')
  auto s_build = [&](int jt, int bw){
    const int qb = jt & 1;
    const _Float16* qa = QTA(qb); const _Float16* qbb = QTB(qb); const _Float16* qc = QTC(qb);
    const float* wqp = WQSP(qb);
    unsigned short* bs = BSP(bw);
    #pragma unroll
    for (int s2 = 0; s2 < 2; ++s2){
      const int f = w * 2 + s2, si = f >> 2, sj = f & 3;
      const int prow = si * 16 + (l & 15), qrow = sj * 16 + (l & 15);
      const half8 ap = *(const half8*)&PTH[prow * 40 + (l >> 4) * 8];
      const half8 bA = *(const half8*)&qa [qrow * 40 + (l >> 4) * 8];
      const half8 bB = *(const half8*)&qbb[qrow * 40 + (l >> 4) * 8];
      const half8 bC = *(const half8*)&qc [qrow * 40 + (l >> 4) * 8];
      const f32x4 z = (f32x4){0.f, 0.f, 0.f, 0.f};
      const f32x4 d1 = __builtin_amdgcn_mfma_f32_16x16x32_f16(ap, bA, z, 0, 0, 0);
      const f32x4 d2 = __builtin_amdgcn_mfma_f32_16x16x32_f16(ap, bB, z, 0, 0, 0);
      const f32x4 d3 = __builtin_amdgcn_mfma_f32_16x16x32_f16(ap, bC, z, 0, 0, 0);
      const float wqv = wqp[qrow];
      #pragma unroll
      for (int r = 0; r < 4; ++r){
        const float S = d1[r] + 0.00390625f * (d2[r] + d3[r]);
        const int irow = si * 16 + (l >> 4) * 4 + r;
        bs[irow * 64 + (((qrow >> 3) ^ (irow & 7)) * 8) + (qrow & 7)]
            = f2h(tanh_fast(S) * wqv);
      }
    }
  };

  // ---- prologue ----
  {
    uint4* z = (uint4*)(pool + 81920);
    for (int idx = t; idx < 2272; idx += 512) z[idx] = (uint4){0, 0, 0, 0};
  }
  __syncthreads();
  stage(0, 0);
  stage(1, 64);
  {
    // P build (fixed all 16 steps)
    const int col = t & 63, lg = t >> 6;
    const float wp = __expf(cvalP[i0 + col] - mP) * rlP;
    #pragma unroll
    for (int u = 0; u < 2; ++u){
      const int lq = lg * 2 + u;
      const float p = wp * pdotP[(size_t)lq * HW_ + i0 + col] + pbP[lq];
      const _Float16 ph = (_Float16)p;
      const _Float16 pl = (_Float16)((p - (float)ph) * 256.0f);
      PTH[col * 40 + lq] = ph;
      PTH[col * 40 + 16 + lq] = pl;
    }
  }
  q_build(0);
  asm volatile("s_waitcnt lgkmcnt(0)" ::: "memory");
  __builtin_amdgcn_sched_barrier(0);
  __builtin_amdgcn_s_barrier();
  s_build(0, 0);
  q_build(1);
  asm volatile("s_waitcnt lgkmcnt(0)" ::: "memory");
  __builtin_amdgcn_sched_barrier(0);
  __builtin_amdgcn_s_barrier();

  // ---- main loop ----
  int cur = 0;
  for (int kt = 0; kt < 16; ++kt){
    if (kt < 15) { asm volatile("s_waitcnt vmcnt(4) lgkmcnt(0)" ::: "memory"); }
    else         { asm volatile("s_waitcnt vmcnt(0) lgkmcnt(0)" ::: "memory"); }
    __builtin_amdgcn_sched_barrier(0);
    __builtin_amdgcn_s_barrier();

    const unsigned short* Xsb = XSP(cur);
    const unsigned short* Bsb = BSP(cur);
    #pragma unroll
    for (int ks = 0; ks < 2; ++ks){
      half8 a[4], bb[2];
      #pragma unroll
      for (int fm = 0; fm < 4; ++fm){
        const int row = wr * 64 + fm * 16 + (l & 15);
        const int kc = (ks * 4 + (l >> 4)) ^ (row & 7);
        a[fm] = *(const half8*)&Xsb[row * 64 + kc * 8];
      }
      #pragma unroll
      for (int fn = 0; fn < 2; ++fn){
        const int row = wc * 32 + fn * 16 + (l & 15);
        const int kc = (ks * 4 + (l >> 4)) ^ (row & 7);
        bb[fn] = *(const half8*)&Bsb[row * 64 + kc * 8];
      }
      #pragma unroll
      for (int fm = 0; fm < 4; ++fm)
        #pragma unroll
        for (int fn = 0; fn < 2; ++fn)
          acc[fm][fn] = __builtin_amdgcn_mfma_f32_16x16x32_f16(a[fm], bb[fn], acc[fm][fn], 0, 0, 0);
    }
    if (kt < 15) s_build(kt + 1, cur ^ 1);

    asm volatile("s_waitcnt lgkmcnt(0)" ::: "memory");
    __builtin_amdgcn_sched_barrier(0);
    __builtin_amdgcn_s_barrier();
    __builtin_amdgcn_sched_barrier(0);

    if (kt < 14){
      q_build(kt + 2);       // globals first (older than GLD16 for counted waits)
      stage(cur, (kt + 2) * 64);
    }
    cur ^= 1;
  }

  // ---- epilogue: L2-norm + resid/relu + next-iter sa-dot (or h/s outputs) ----
  float* pwT   = (float*)pool;             // [256][20] over dead Xs
  float* redp  = (float*)(pool + 32768);   // [4][2][2][17][16]
  float* ssred = (float*)(pool + 65536);   // [4][64] over dead Bs
  float* rinvp = (float*)(pool + 66560);   // [64]

  float ss0 = 0.f, ss1 = 0.f;
  #pragma unroll
  for (int fm = 0; fm < 4; ++fm)
    #pragma unroll
    for (int r = 0; r < 4; ++r){
      ss0 += acc[fm][0][r] * acc[fm][0][r];
      ss1 += acc[fm][1][r] * acc[fm][1][r];
    }
  ss0 += __shfl_xor(ss0, 16); ss0 += __shfl_xor(ss0, 32);
  ss1 += __shfl_xor(ss1, 16); ss1 += __shfl_xor(ss1, 32);
  if (l < 16){
    ssred[wr * 64 + wc * 32 + l]      = ss0;
    ssred[wr * 64 + wc * 32 + 16 + l] = ss1;
  }

  if (!last){
    const float* __restrict__ pw = g ? pw2 : pw1;
    const float* __restrict__ cw = g ? cw2 : cw1;
    {
      const int idx = t * 8;
      const int lq = idx >> 8, c = idx & 255;
      const float4 p0 = *(const float4*)&pw[lq * C_ + c];
      const float4 p1 = *(const float4*)&pw[lq * C_ + c + 4];
      pwT[(c + 0) * 20 + lq] = p0.x; pwT[(c + 1) * 20 + lq] = p0.y;
      pwT[(c + 2) * 20 + lq] = p0.z; pwT[(c + 3) * 20 + lq] = p0.w;
      pwT[(c + 4) * 20 + lq] = p1.x; pwT[(c + 5) * 20 + lq] = p1.y;
      pwT[(c + 6) * 20 + lq] = p1.z; pwT[(c + 7) * 20 + lq] = p1.w;
    }
    if (t < 32){
      const float4 c0 = *(const float4*)&cw[t * 8];
      const float4 c1 = *(const float4*)&cw[t * 8 + 4];
      pwT[(t * 8 + 0) * 20 + 16] = c0.x; pwT[(t * 8 + 1) * 20 + 16] = c0.y;
      pwT[(t * 8 + 2) * 20 + 16] = c0.z; pwT[(t * 8 + 3) * 20 + 16] = c0.w;
      pwT[(t * 8 + 4) * 20 + 16] = c1.x; pwT[(t * 8 + 5) * 20 + 16] = c1.y;
      pwT[(t * 8 + 6) * 20 + 16] = c1.z; pwT[(t * 8 + 7) * 20 + 16] = c1.w;
    }
  }
  __syncthreads();
  if (t < 64){
    const float s = ssred[t] + ssred[64 + t] + ssred[128 + t] + ssred[192 + t];
    rinvp[t] = 1.f / fmaxf(sqrtf(s), 1e-12f);
  }
  __syncthreads();
  const float ri[2] = { rinvp[wc * 32 + (l & 15)], rinvp[wc * 32 + 16 + (l & 15)] };

  const float* __restrict__ fpin = (g ? fpin2 : fpin1) + (size_t)n * C_ * HW_;
  float* __restrict__ fpo  = (g ? fpo2 : fpo1) + (size_t)n * C_ * HW_;
  _Float16* __restrict__ fhn = (g ? fhn2 : fhn1) + (size_t)n * C_ * HW_;
  float* __restrict__ outp = out + (size_t)g * SZ_ + (size_t)n * C_ * HW_;
  const int rbase = (l >> 4) * 4, col = l & 15;
  const int baseio = n * 2 + g;

  if (!last){
    float sacc[2][17];
    #pragma unroll
    for (int fn = 0; fn < 2; ++fn)
      #pragma unroll
      for (int lq = 0; lq < 17; ++lq) sacc[fn][lq] = 0.f;

    #pragma unroll
    for (int fm = 0; fm < 4; ++fm)
      #pragma unroll
      for (int r = 0; r < 4; ++r){
        const int c = wr * 64 + fm * 16 + rbase + r;
        float prow[17];
        #pragma unroll
        for (int q4 = 0; q4 < 4; ++q4){
          const float4 pv = *(const float4*)&pwT[c * 20 + q4 * 4];
          prow[q4 * 4 + 0] = pv.x; prow[q4 * 4 + 1] = pv.y;
          prow[q4 * 4 + 2] = pv.z; prow[q4 * 4 + 3] = pv.w;
        }
        prow[16] = pwT[c * 20 + 16];
        #pragma unroll
        for (int fn = 0; fn < 2; ++fn){
          const size_t base = (size_t)c * HW_ + i0 + wc * 32 + fn * 16 + col;
          const float h = acc[fm][fn][r] * ri[fn];
          const float fv = fpin[base] + h;
          const float rv = fv > 0.f ? fv : 0.f;
          fpo[base] = rv;
          fhn[base] = (_Float16)rv;
          #pragma unroll
          for (int lq = 0; lq < 17; ++lq) sacc[fn][lq] += rv * prow[lq];
        }
      }

    #pragma unroll
    for (int fn = 0; fn < 2; ++fn)
      #pragma unroll
      for (int lq = 0; lq < 17; ++lq){
        float v = sacc[fn][lq];
        v += __shfl_xor(v, 16);
        v += __shfl_xor(v, 32);
        sacc[fn][lq] = v;
      }
    if (l < 16){
      #pragma unroll
      for (int fn = 0; fn < 2; ++fn)
        #pragma unroll
        for (int lq = 0; lq < 17; ++lq)
          redp[(((wr * 2 + wc) * 2 + fn) * 17 + lq) * 16 + l] = sacc[fn][lq];
    }
    __syncthreads();
    if (t < 64){
      const int wcx = t >> 5, fnx = (t >> 4) & 1, colx = t & 15;
      float xc = 0.f;
      #pragma unroll
      for (int lq = 0; lq < 17; ++lq){
        float s = 0.f;
        #pragma unroll
        for (int wrx = 0; wrx < 4; ++wrx)
          s += redp[(((wrx * 2 + wcx) * 2 + fnx) * 17 + lq) * 16 + colx];
        if (lq < 16) pdot[((size_t)baseio * CL_ + lq) * HW_ + i0 + t] = s;
        else       { cval[(size_t)baseio * HW_ + i0 + t] = s; xc = s; }
      }
      float mb = xc;
      #pragma unroll
      for (int off = 32; off; off >>= 1) mb = fmaxf(mb, __shfl_xor(mb, off));
      float e = __expf(xc - mb);
      #pragma unroll
      for (int off = 32; off; off >>= 1) e += __shfl_xor(e, off);
      if (t == 0){
        mpart[baseio * 16 + (i0 >> 6)] = mb;
        spart[baseio * 16 + (i0 >> 6)] = e;
      }
    }
  } else {
    // h output + s output (s = w * fp_last); baseQ == n*2+g, mQ/rlQ already computed
    float* __restrict__ out2p = out + (size_t)(2 + g) * SZ_ + (size_t)n * C_ * HW_;
    float wv[2];
    #pragma unroll
    for (int fn = 0; fn < 2; ++fn)
      wv[fn] = __expf(cvalQ[i0 + wc * 32 + fn * 16 + col] - mQ) * rlQ;
    #pragma unroll
    for (int fm = 0; fm < 4; ++fm)
      #pragma unroll
      for (int fn = 0; fn < 2; ++fn){
        const size_t base = (size_t)(wr * 64 + fm * 16 + rbase) * HW_ + i0 + wc * 32 + fn * 16 + col;
        #pragma unroll
        for (int r = 0; r < 4; ++r){
          outp[base + (size_t)r * HW_] = acc[fm][fn][r] * ri[fn];
          out2p[base + (size_t)r * HW_] = wv[fn] * fpin[base + (size_t)r * HW_];
        }
      }
  }
  #undef XSP
  #undef BSP
  #undef QTA
  #undef QTB
  #undef QTC
  #undef PTH
  #undef WQSP
}

extern "C" void kernel_launch(void* const* d_in, const int* in_sizes, int n_in,
                              void* d_out, int out_size, void* d_ws, size_t ws_size,
                              hipStream_t stream)
{
  const float* f1  = (const float*)d_in[0];
  const float* f2  = (const float*)d_in[1];
  const float* pw1 = (const float*)d_in[2];
  const float* pb1 = (const float*)d_in[3];
  const float* pw2 = (const float*)d_in[4];
  const float* pb2 = (const float*)d_in[5];
  const float* cw1 = (const float*)d_in[6];
  const float* cw2 = (const float*)d_in[8];
  // cb1/cb2 unused: softmax is shift-invariant
  float* out = (float*)d_out;
  float* ws  = (float*)d_ws;

  float* cval  = ws;                           // 16K f32
  float* pdot  = cval + N_ * 2 * HW_;          // 256K f32
  float* mpart = pdot + N_ * 2 * CL_ * HW_;    // 512
  float* spart = mpart + 512;                  // 512
  float* fp1   = spart + 512;                  // SZ_ f32 state
  float* fp2   = fp1 + SZ_;                    // SZ_ f32 state
  _Float16* fhA1 = (_Float16*)(fp2 + SZ_);     // SZ_ fp16 mirror (ping)
  _Float16* fhA2 = fhA1 + SZ_;
  _Float16* fhB1 = fhA2 + SZ_;                 // SZ_ fp16 mirror (pong)
  _Float16* fhB2 = fhB1 + SZ_;

  k_sa_dot<<<dim3(16, 2, 8), 256, 0, stream>>>(f1, f2, cw1, cw2, pw1, pw2,
                                               cval, pdot, mpart, spart, fhA1, fhA2);

  for (int it = 0; it < 5; ++it){
    const float* cur1 = (it == 0) ? f1 : fp1;
    const float* cur2 = (it == 0) ? f2 : fp2;
    const _Float16* fhc1 = (it & 1) ? fhB1 : fhA1;
    const _Float16* fhc2 = (it & 1) ? fhB2 : fhA2;
    _Float16* fhn1 = (it & 1) ? fhA1 : fhB1;
    _Float16* fhn2 = (it & 1) ? fhA2 : fhB2;

    k_flash<<<dim3(16, 2, 8), 512, 0, stream>>>(fhc1, fhc2,
                                                cur1, cur2, fp1, fp2, fhn1, fhn2,
                                                pw1, pw2, cw1, cw2, pb1, pb2,
                                                cval, pdot, mpart, spart,
                                                out, (it == 4) ? 1 : 0);
  }
}